// Round 1
// baseline (668.901 us; speedup 1.0000x reference)
//
#include <hip/hip_runtime.h>
#include <math.h>

// ---------------------------------------------------------------------------
// GCN: 3 layers of { h = x@W ; agg[dst] += h[src]*norm ; relu(agg + b) },
// then log_softmax. norm = dinv[src]*dinv[dst], deg counted over dst incl.
// self-loops. Self-loop contribution = h[i]*dinv[i]^2, folded into agg init.
// ---------------------------------------------------------------------------

#define D_FEAT 64

__global__ void init_deg_kernel(float* __restrict__ deg, int n) {
    int i = blockIdx.x * blockDim.x + threadIdx.x;
    if (i < n) deg[i] = 1.0f;   // self-loop
}

__global__ void count_deg_kernel(const int* __restrict__ dst, float* __restrict__ deg, int e) {
    int i = blockIdx.x * blockDim.x + threadIdx.x;
    if (i < e) atomicAdd(&deg[dst[i]], 1.0f);
}

__global__ void dinv_kernel(float* __restrict__ dinv, int n) {
    int i = blockIdx.x * blockDim.x + threadIdx.x;
    if (i < n) dinv[i] = rsqrtf(dinv[i]);   // deg >= 1 always (self-loop)
}

__global__ void norm_kernel(const int* __restrict__ src, const int* __restrict__ dst,
                            const float* __restrict__ dinv, float* __restrict__ norm, int e) {
    int i = blockIdx.x * blockDim.x + threadIdx.x;
    if (i < e) norm[i] = dinv[src[i]] * dinv[dst[i]];
}

// H[M x NC] = X[M x 64] @ W[64 x NC].  Block: (64,4) threads, 4 rows/block.
template <int NC>
__global__ void gemm_kernel(const float* __restrict__ X, const float* __restrict__ W,
                            float* __restrict__ H, int M) {
    __shared__ float Ws[64 * NC];
    __shared__ float Xs[4][64];
    const int tx = threadIdx.x;           // 0..63
    const int ty = threadIdx.y;           // 0..3
    const int tid = ty * 64 + tx;
    for (int i = tid; i < 64 * NC; i += 256) Ws[i] = W[i];
    const int row = blockIdx.x * 4 + ty;
    Xs[ty][tx] = (row < M) ? X[row * 64 + tx] : 0.0f;
    __syncthreads();
    if (row < M && tx < NC) {
        float acc = 0.0f;
#pragma unroll
        for (int k = 0; k < 64; ++k) acc += Xs[ty][k] * Ws[k * NC + tx];
        H[row * NC + tx] = acc;
    }
}

// agg[i,c] = h[i,c]*dinv[i]^2 + b[c]   (pure write: initializes poisoned ws)
template <int NC>
__global__ void selfinit_kernel(const float* __restrict__ H, const float* __restrict__ dinv,
                                const float* __restrict__ b, float* __restrict__ AGG, int M) {
    int i = blockIdx.x * blockDim.x + threadIdx.x;
    if (i >= M * NC) return;
    int n = i / NC, c = i % NC;
    float di = dinv[n];
    AGG[i] = H[i] * di * di + b[c];
}

// one thread per (edge, col): agg[dst,c] += h[src,c]*norm[e]
template <int NC>
__global__ void scatter_kernel(const int* __restrict__ src, const int* __restrict__ dst,
                               const float* __restrict__ norm, const float* __restrict__ H,
                               float* __restrict__ AGG, int total) {
    int i = blockIdx.x * blockDim.x + threadIdx.x;
    if (i >= total) return;
    int e = i / NC, c = i % NC;
    int s = src[e], d = dst[e];
    atomicAdd(&AGG[d * NC + c], H[s * NC + c] * norm[e]);
}

__global__ void relu_kernel(float* __restrict__ x, int total) {
    int i = blockIdx.x * blockDim.x + threadIdx.x;
    if (i < total) x[i] = fmaxf(x[i], 0.0f);
}

// relu then log_softmax over NC=40 classes; one wave (64 lanes) per row.
__global__ void lsm_kernel(const float* __restrict__ AGG, float* __restrict__ out,
                           int M, int NC) {
    const int wave = threadIdx.x >> 6;          // 0..3
    const int lane = threadIdx.x & 63;
    const int row = blockIdx.x * 4 + wave;
    if (row >= M) return;
    float v = (lane < NC) ? fmaxf(AGG[row * NC + lane], 0.0f) : -INFINITY;
    float m = v;
#pragma unroll
    for (int o = 32; o; o >>= 1) m = fmaxf(m, __shfl_xor(m, o, 64));
    float ex = (lane < NC) ? expf(v - m) : 0.0f;
    float s = ex;
#pragma unroll
    for (int o = 32; o; o >>= 1) s += __shfl_xor(s, o, 64);
    if (lane < NC) out[row * NC + lane] = v - m - logf(s);
}

extern "C" void kernel_launch(void* const* d_in, const int* in_sizes, int n_in,
                              void* d_out, int out_size, void* d_ws, size_t ws_size,
                              hipStream_t stream) {
    const float* x   = (const float*)d_in[0];
    const int*   ei  = (const int*)d_in[1];       // [2, E] int32 (JAX x64 disabled)
    const float* W1  = (const float*)d_in[2];
    const float* b1  = (const float*)d_in[3];
    const float* W2  = (const float*)d_in[4];
    const float* b2  = (const float*)d_in[5];
    const float* W3  = (const float*)d_in[6];
    const float* b3  = (const float*)d_in[7];
    float* out = (float*)d_out;

    const int M  = in_sizes[0] / D_FEAT;          // 50000
    const int E  = in_sizes[1] / 2;               // 800000
    const int NC = in_sizes[7];                   // 40 (b3 size)

    const int* src = ei;
    const int* dst = ei + E;

    // workspace layout (floats), 64-float aligned
    float* ws = (float*)d_ws;
    size_t off = 0;
    float* dinv = ws + off;  off += ((size_t)M + 63) & ~63ull;
    float* norm = ws + off;  off += ((size_t)E + 63) & ~63ull;
    float* A    = ws + off;  off += (size_t)M * D_FEAT;
    float* B    = ws + off;  off += (size_t)M * D_FEAT;
    (void)ws_size;

    const int TB = 256;
    const int gN = (M + TB - 1) / TB;
    const int gE = (E + TB - 1) / TB;

    // --- normalization coefficients ---
    init_deg_kernel<<<gN, TB, 0, stream>>>(dinv, M);
    count_deg_kernel<<<gE, TB, 0, stream>>>(dst, dinv, E);
    dinv_kernel<<<gN, TB, 0, stream>>>(dinv, M);
    norm_kernel<<<gE, TB, 0, stream>>>(src, dst, dinv, norm, E);

    const dim3 gemmBlk(64, 4);
    const int  gemmGrd = (M + 3) / 4;

    // --- layer 1: x -> B ---
    gemm_kernel<64><<<gemmGrd, gemmBlk, 0, stream>>>(x, W1, A, M);
    selfinit_kernel<64><<<(M * 64 + TB - 1) / TB, TB, 0, stream>>>(A, dinv, b1, B, M);
    scatter_kernel<64><<<(E * 64 + TB - 1) / TB, TB, 0, stream>>>(src, dst, norm, A, B, E * 64);
    relu_kernel<<<(M * 64 + TB - 1) / TB, TB, 0, stream>>>(B, M * 64);

    // --- layer 2: B -> B ---
    gemm_kernel<64><<<gemmGrd, gemmBlk, 0, stream>>>(B, W2, A, M);
    selfinit_kernel<64><<<(M * 64 + TB - 1) / TB, TB, 0, stream>>>(A, dinv, b2, B, M);
    scatter_kernel<64><<<(E * 64 + TB - 1) / TB, TB, 0, stream>>>(src, dst, norm, A, B, E * 64);
    relu_kernel<<<(M * 64 + TB - 1) / TB, TB, 0, stream>>>(B, M * 64);

    // --- layer 3: B -> B (40 cols) ---
    gemm_kernel<40><<<gemmGrd, gemmBlk, 0, stream>>>(B, W3, A, M);
    selfinit_kernel<40><<<(M * 40 + TB - 1) / TB, TB, 0, stream>>>(A, dinv, b3, B, M);
    scatter_kernel<40><<<(E * 40 + TB - 1) / TB, TB, 0, stream>>>(src, dst, norm, A, B, E * 40);

    // --- relu + log_softmax -> out ---
    lsm_kernel<<<(M + 3) / 4, TB, 0, stream>>>(B, out, M, NC);
}

// Round 2
// 308.212 us; speedup vs baseline: 2.1703x; 2.1703x over previous
//
#include <hip/hip_runtime.h>
#include <math.h>

// ---------------------------------------------------------------------------
// GCN, atomic-free aggregation via per-call CSR (bucket by dst):
//   deg count -> block scan -> fill (atomic cursor)            [once]
//   per layer: g = (x@W)*dinv[row]  (GEMM, W in LDS)
//              y[i] = relu( dinv[i]*(g[i] + sum_{e: dst=i} g[src_e]) + b )
//   layer 3 fuses log_softmax (one wave owns the whole 40-col row).
// ---------------------------------------------------------------------------

#define DF 64
#define TB 256

__global__ void zero_int_kernel(int* __restrict__ p, int n) {
    int i = blockIdx.x * blockDim.x + threadIdx.x;
    if (i < n) p[i] = 0;
}

__global__ void count_deg_kernel(const int* __restrict__ dst, int* __restrict__ deg, int e) {
    int i = blockIdx.x * blockDim.x + threadIdx.x;
    if (i < e) atomicAdd(&deg[dst[i]], 1);
}

__global__ void dinv_kernel(const int* __restrict__ deg, float* __restrict__ dinv, int n) {
    int i = blockIdx.x * blockDim.x + threadIdx.x;
    if (i < n) dinv[i] = rsqrtf((float)(deg[i] + 1));   // +1 self-loop
}

// per-block exclusive scan of deg -> rowptr (partial), block totals -> bsum
__global__ void scan_block_kernel(const int* __restrict__ deg, int* __restrict__ ex,
                                  int* __restrict__ bsum, int n) {
    __shared__ int s[TB];
    const int t = threadIdx.x;
    const int i = blockIdx.x * TB + t;
    int v = (i < n) ? deg[i] : 0;
    s[t] = v; __syncthreads();
#pragma unroll
    for (int o = 1; o < TB; o <<= 1) {
        int u = (t >= o) ? s[t - o] : 0;
        __syncthreads();
        s[t] += u;
        __syncthreads();
    }
    if (i < n) ex[i] = s[t] - v;
    if (t == TB - 1) bsum[blockIdx.x] = s[TB - 1];
}

// exclusive scan of block sums (nb <= 256)
__global__ void scan_sums_kernel(int* __restrict__ bsum, int nb) {
    __shared__ int s[TB];
    const int t = threadIdx.x;
    int v = (t < nb) ? bsum[t] : 0;
    s[t] = v; __syncthreads();
#pragma unroll
    for (int o = 1; o < TB; o <<= 1) {
        int u = (t >= o) ? s[t - o] : 0;
        __syncthreads();
        s[t] += u;
        __syncthreads();
    }
    if (t < nb) bsum[t] = s[t] - v;
}

__global__ void add_offsets_kernel(int* __restrict__ ex, const int* __restrict__ bsum,
                                   int* __restrict__ cursor, int n) {
    int i = blockIdx.x * blockDim.x + threadIdx.x;
    if (i < n) {
        int r = ex[i] + bsum[blockIdx.x];   // grid uses TB=256 to match scan blocks
        ex[i] = r;
        cursor[i] = r;
    }
}

__global__ void fill_csr_kernel(const int* __restrict__ src, const int* __restrict__ dst,
                                int* __restrict__ cursor, int* __restrict__ cidx, int e) {
    int i = blockIdx.x * blockDim.x + threadIdx.x;
    if (i < e) {
        int pos = atomicAdd(&cursor[dst[i]], 1);
        cidx[pos] = src[i];
    }
}

// G[M x NC] = (X[M x 64] @ W[64 x NC]) * dinv[row].  Block (64,8).
template <int NC>
__global__ __launch_bounds__(512) void gemm_kernel(const float* __restrict__ X,
                                                   const float* __restrict__ W,
                                                   const float* __restrict__ dinv,
                                                   float* __restrict__ G, int M) {
    __shared__ float Ws[64 * NC];
    __shared__ float Xs[8][64];
    const int tx = threadIdx.x;           // 0..63
    const int ty = threadIdx.y;           // 0..7
    const int tid = ty * 64 + tx;
    for (int i = tid; i < 64 * NC; i += 512) Ws[i] = W[i];
    const int row = blockIdx.x * 8 + ty;
    Xs[ty][tx] = (row < M) ? X[(size_t)row * 64 + tx] : 0.0f;
    __syncthreads();
    if (row < M && tx < NC) {
        float acc = 0.0f;
#pragma unroll
        for (int k = 0; k < 64; ++k) acc += Xs[ty][k] * Ws[k * NC + tx];
        G[(size_t)row * NC + tx] = acc * dinv[row];
    }
}

// One wave per node: acc = g[i] + sum of g[src] over in-edges; y = relu(dinv[i]*acc + b)
// LSM=true additionally applies log_softmax across the row (NC <= 64).
template <int NC, bool LSM>
__global__ void agg_kernel(const float* __restrict__ G, const int* __restrict__ rowptr,
                           const int* __restrict__ deg, const int* __restrict__ cidx,
                           const float* __restrict__ dinv, const float* __restrict__ b,
                           float* __restrict__ Y, int M) {
    const int lane = threadIdx.x & 63;
    const int node = blockIdx.x * 4 + (threadIdx.x >> 6);
    if (node >= M) return;
    const bool act = (lane < NC);
    const int start = rowptr[node];
    const int cnt = deg[node];

    float a0 = act ? G[(size_t)node * NC + lane] : 0.0f;   // self term
    float a1 = 0.0f, a2 = 0.0f, a3 = 0.0f;
    int j = 0;
    for (; j + 3 < cnt; j += 4) {
        int s0 = cidx[start + j];
        int s1 = cidx[start + j + 1];
        int s2 = cidx[start + j + 2];
        int s3 = cidx[start + j + 3];
        if (act) {
            a0 += G[(size_t)s0 * NC + lane];
            a1 += G[(size_t)s1 * NC + lane];
            a2 += G[(size_t)s2 * NC + lane];
            a3 += G[(size_t)s3 * NC + lane];
        }
    }
    for (; j < cnt; ++j) {
        int s = cidx[start + j];
        if (act) a1 += G[(size_t)s * NC + lane];
    }
    float v = (a0 + a1 + a2 + a3) * dinv[node] + (act ? b[lane] : 0.0f);
    v = fmaxf(v, 0.0f);

    if (!LSM) {
        if (act) Y[(size_t)node * NC + lane] = v;
        return;
    }
    float vm = act ? v : -INFINITY;
    float m = vm;
#pragma unroll
    for (int o = 32; o; o >>= 1) m = fmaxf(m, __shfl_xor(m, o, 64));
    float ex = act ? expf(vm - m) : 0.0f;
    float s = ex;
#pragma unroll
    for (int o = 32; o; o >>= 1) s += __shfl_xor(s, o, 64);
    if (act) Y[(size_t)node * NC + lane] = vm - m - logf(s);
}

extern "C" void kernel_launch(void* const* d_in, const int* in_sizes, int n_in,
                              void* d_out, int out_size, void* d_ws, size_t ws_size,
                              hipStream_t stream) {
    const float* x  = (const float*)d_in[0];
    const int*   ei = (const int*)d_in[1];        // [2, E] int32
    const float* W1 = (const float*)d_in[2];
    const float* b1 = (const float*)d_in[3];
    const float* W2 = (const float*)d_in[4];
    const float* b2 = (const float*)d_in[5];
    const float* W3 = (const float*)d_in[6];
    const float* b3 = (const float*)d_in[7];
    float* out = (float*)d_out;

    const int M  = in_sizes[0] / DF;              // 50000
    const int E  = in_sizes[1] / 2;               // 800000
    const int NC = in_sizes[7];                   // 40
    (void)NC; (void)ws_size; (void)n_in; (void)out_size;

    const int* src = ei;
    const int* dst = ei + E;

    const size_t Ma = ((size_t)M + 63) & ~63ull;
    const size_t Ea = ((size_t)E + 63) & ~63ull;

    // workspace layout
    int* deg    = (int*)d_ws;          // M
    int* rowptr = deg + Ma;            // M
    int* cursor = rowptr + Ma;         // M
    int* bsum   = cursor + Ma;         // 256
    int* cidx   = bsum + 256;          // E
    float* dinv = (float*)(cidx + Ea); // M
    float* A    = dinv + Ma;           // M*64  (gemm out, pre-scaled)
    float* B    = A + Ma * DF;         // M*64  (agg out / next layer in)

    const int gN = (M + TB - 1) / TB;
    const int gE = (E + TB - 1) / TB;
    const int nb = (M + TB - 1) / TB;  // scan blocks (196 <= 256)

    // --- CSR build + dinv (once, reused by all 3 layers) ---
    zero_int_kernel<<<gN, TB, 0, stream>>>(deg, M);
    count_deg_kernel<<<gE, TB, 0, stream>>>(dst, deg, E);
    dinv_kernel<<<gN, TB, 0, stream>>>(deg, dinv, M);
    scan_block_kernel<<<nb, TB, 0, stream>>>(deg, rowptr, bsum, M);
    scan_sums_kernel<<<1, TB, 0, stream>>>(bsum, nb);
    add_offsets_kernel<<<nb, TB, 0, stream>>>(rowptr, bsum, cursor, M);
    fill_csr_kernel<<<gE, TB, 0, stream>>>(src, dst, cursor, cidx, E);

    const dim3 gemmBlk(64, 8);
    const int  gemmGrd = (M + 7) / 8;
    const int  aggGrd  = (M + 3) / 4;

    // --- layer 1 ---
    gemm_kernel<64><<<gemmGrd, gemmBlk, 0, stream>>>(x, W1, dinv, A, M);
    agg_kernel<64, false><<<aggGrd, TB, 0, stream>>>(A, rowptr, deg, cidx, dinv, b1, B, M);
    // --- layer 2 ---
    gemm_kernel<64><<<gemmGrd, gemmBlk, 0, stream>>>(B, W2, dinv, A, M);
    agg_kernel<64, false><<<aggGrd, TB, 0, stream>>>(A, rowptr, deg, cidx, dinv, b2, B, M);
    // --- layer 3 (40 cols) + fused log_softmax ---
    gemm_kernel<40><<<gemmGrd, gemmBlk, 0, stream>>>(B, W3, dinv, A, M);
    agg_kernel<40, true><<<aggGrd, TB, 0, stream>>>(A, rowptr, deg, cidx, dinv, b3, out, M);
}

// Round 3
// 242.422 us; speedup vs baseline: 2.7592x; 1.2714x over previous
//
#include <hip/hip_runtime.h>
#include <math.h>

// ---------------------------------------------------------------------------
// GCN, atomic-free aggregation via per-call CSR (bucket by dst):
//   deg count -> block scan(+dinv) -> fill (atomic cursor, u16 cidx)  [once]
//   per layer: G = (X@W)*dinv[row]  (GEMM, W in LDS, bf16 output)
//              y[i] = relu( dinv[i]*(G[i] + sum_{e: dst=i} G[src_e]) + b )
//   layer 3 fuses log_softmax (one wave owns the whole 40-col row).
// cidx is uint16: valid because N_NODES=50000 < 65536.
// ---------------------------------------------------------------------------

#define DF 64
#define TB 256

__device__ __forceinline__ unsigned short f2bf(float f) {
    union { float f; unsigned u; } c; c.f = f;
    unsigned u = c.u;
    return (unsigned short)((u + 0x7fffu + ((u >> 16) & 1u)) >> 16);   // RNE
}
__device__ __forceinline__ float bf2f(unsigned short h) {
    union { unsigned u; float f; } c; c.u = ((unsigned)h) << 16;
    return c.f;
}

__global__ void zero_int_kernel(int* __restrict__ p, int n) {
    int i = blockIdx.x * blockDim.x + threadIdx.x;
    if (i < n) p[i] = 0;
}

__global__ void count_deg_kernel(const int* __restrict__ dst, int* __restrict__ deg, int e) {
    int i = blockIdx.x * blockDim.x + threadIdx.x;
    if (i < e) atomicAdd(&deg[dst[i]], 1);
}

// per-block exclusive scan of deg -> ex (partial), block totals -> bsum; also dinv
__global__ void scan_block_kernel(const int* __restrict__ deg, int* __restrict__ ex,
                                  int* __restrict__ bsum, float* __restrict__ dinv, int n) {
    __shared__ int s[TB];
    const int t = threadIdx.x;
    const int i = blockIdx.x * TB + t;
    int v = (i < n) ? deg[i] : 0;
    if (i < n) dinv[i] = rsqrtf((float)(v + 1));   // +1 self-loop
    s[t] = v; __syncthreads();
#pragma unroll
    for (int o = 1; o < TB; o <<= 1) {
        int u = (t >= o) ? s[t - o] : 0;
        __syncthreads();
        s[t] += u;
        __syncthreads();
    }
    if (i < n) ex[i] = s[t] - v;
    if (t == TB - 1) bsum[blockIdx.x] = s[TB - 1];
}

// exclusive scan of block sums (nb <= 256)
__global__ void scan_sums_kernel(int* __restrict__ bsum, int nb) {
    __shared__ int s[TB];
    const int t = threadIdx.x;
    int v = (t < nb) ? bsum[t] : 0;
    s[t] = v; __syncthreads();
#pragma unroll
    for (int o = 1; o < TB; o <<= 1) {
        int u = (t >= o) ? s[t - o] : 0;
        __syncthreads();
        s[t] += u;
        __syncthreads();
    }
    if (t < nb) bsum[t] = s[t] - v;
}

__global__ void add_offsets_kernel(int* __restrict__ ex, const int* __restrict__ bsum,
                                   int* __restrict__ cursor, int n) {
    int i = blockIdx.x * blockDim.x + threadIdx.x;
    if (i < n) {
        int r = ex[i] + bsum[blockIdx.x];   // grid uses TB blocks matching scan
        ex[i] = r;
        cursor[i] = r;
    }
}

__global__ void fill_csr_kernel(const int* __restrict__ src, const int* __restrict__ dst,
                                int* __restrict__ cursor, unsigned short* __restrict__ cidx,
                                int e) {
    int i = blockIdx.x * blockDim.x + threadIdx.x;
    if (i < e) {
        int pos = atomicAdd(&cursor[dst[i]], 1);
        cidx[pos] = (unsigned short)src[i];
    }
}

// G[M x NC](bf16) = (X[M x 64] @ W[64 x NC]) * dinv[row].
// Block (16,16): 16 rows/block, each thread computes 4 cols via float4 W reads.
template <int NC>
__global__ __launch_bounds__(256) void gemm_kernel(const float* __restrict__ X,
                                                   const float* __restrict__ W,
                                                   const float* __restrict__ dinv,
                                                   unsigned short* __restrict__ G, int M) {
    __shared__ float Ws[64 * NC];
    __shared__ float Xs[16][65];
    const int tx = threadIdx.x;            // 0..15 col group
    const int ty = threadIdx.y;            // 0..15 row
    const int tid = ty * 16 + tx;
    for (int i = tid; i < 64 * NC / 4; i += 256)
        ((float4*)Ws)[i] = ((const float4*)W)[i];
    const int row0 = blockIdx.x * 16;
    {   // stage 16 rows of X: 256 threads x float4
        int r = tid / 16, c4 = tid % 16;
        float4 v = (row0 + r < M) ? ((const float4*)(X + (size_t)(row0 + r) * 64))[c4]
                                  : make_float4(0.f, 0.f, 0.f, 0.f);
        Xs[r][c4 * 4 + 0] = v.x; Xs[r][c4 * 4 + 1] = v.y;
        Xs[r][c4 * 4 + 2] = v.z; Xs[r][c4 * 4 + 3] = v.w;
    }
    __syncthreads();
    const int row = row0 + ty;
    const int c0 = tx * 4;
    if (row < M && c0 < NC) {
        float a0 = 0.f, a1 = 0.f, a2 = 0.f, a3 = 0.f;
#pragma unroll
        for (int k = 0; k < 64; ++k) {
            float xk = Xs[ty][k];
            float4 w = ((const float4*)(Ws + (size_t)k * NC))[tx];
            a0 += xk * w.x; a1 += xk * w.y; a2 += xk * w.z; a3 += xk * w.w;
        }
        float di = dinv[row];
        ushort4 o;
        o.x = f2bf(a0 * di); o.y = f2bf(a1 * di);
        o.z = f2bf(a2 * di); o.w = f2bf(a3 * di);
        *((ushort4*)(G + (size_t)row * NC + c0)) = o;
    }
}

// One wave per node: acc = G[i] + sum of G[src] over in-edges;
// y = relu(dinv[i]*acc + b).  LSM=true: fused log_softmax across the row.
template <int NC, bool LSM>
__global__ void agg_kernel(const unsigned short* __restrict__ G,
                           const int* __restrict__ rowptr, const int* __restrict__ deg,
                           const unsigned short* __restrict__ cidx,
                           const float* __restrict__ dinv, const float* __restrict__ b,
                           float* __restrict__ Y, int M) {
    const int lane = threadIdx.x & 63;
    const int node = blockIdx.x * 4 + (threadIdx.x >> 6);
    if (node >= M) return;
    const bool act = (lane < NC);
    const int start = rowptr[node];
    const int cnt = deg[node];

    float a0 = act ? bf2f(G[(size_t)node * NC + lane]) : 0.0f;   // self term
    float a1 = 0.f, a2 = 0.f, a3 = 0.f;
    int j = 0;
    for (; j + 3 < cnt; j += 4) {
        int s0 = cidx[start + j];
        int s1 = cidx[start + j + 1];
        int s2 = cidx[start + j + 2];
        int s3 = cidx[start + j + 3];
        if (act) {
            a0 += bf2f(G[(size_t)s0 * NC + lane]);
            a1 += bf2f(G[(size_t)s1 * NC + lane]);
            a2 += bf2f(G[(size_t)s2 * NC + lane]);
            a3 += bf2f(G[(size_t)s3 * NC + lane]);
        }
    }
    for (; j < cnt; ++j) {
        int s = cidx[start + j];
        if (act) a1 += bf2f(G[(size_t)s * NC + lane]);
    }
    float v = (a0 + a1 + a2 + a3) * dinv[node] + (act ? b[lane] : 0.0f);
    v = fmaxf(v, 0.0f);

    if (!LSM) {
        if (act) Y[(size_t)node * NC + lane] = v;
        return;
    }
    float vm = act ? v : -INFINITY;
    float m = vm;
#pragma unroll
    for (int o = 32; o; o >>= 1) m = fmaxf(m, __shfl_xor(m, o, 64));
    float ex = act ? expf(vm - m) : 0.0f;
    float s = ex;
#pragma unroll
    for (int o = 32; o; o >>= 1) s += __shfl_xor(s, o, 64);
    if (act) Y[(size_t)node * NC + lane] = vm - m - logf(s);
}

extern "C" void kernel_launch(void* const* d_in, const int* in_sizes, int n_in,
                              void* d_out, int out_size, void* d_ws, size_t ws_size,
                              hipStream_t stream) {
    const float* x  = (const float*)d_in[0];
    const int*   ei = (const int*)d_in[1];        // [2, E] int32
    const float* W1 = (const float*)d_in[2];
    const float* b1 = (const float*)d_in[3];
    const float* W2 = (const float*)d_in[4];
    const float* b2 = (const float*)d_in[5];
    const float* W3 = (const float*)d_in[6];
    const float* b3 = (const float*)d_in[7];
    float* out = (float*)d_out;

    const int M  = in_sizes[0] / DF;              // 50000
    const int E  = in_sizes[1] / 2;               // 800000
    (void)ws_size; (void)n_in; (void)out_size;

    const int* src = ei;
    const int* dst = ei + E;

    const size_t Ma = ((size_t)M + 63) & ~63ull;
    const size_t Ea = ((size_t)E + 63) & ~63ull;

    // workspace layout
    int* deg    = (int*)d_ws;                        // Ma
    int* rowptr = deg + Ma;                          // Ma
    int* cursor = rowptr + Ma;                       // Ma
    int* bsum   = cursor + Ma;                       // 256
    unsigned short* cidx = (unsigned short*)(bsum + 256);   // Ea (u16)
    float* dinv = (float*)(cidx + Ea);               // Ma
    unsigned short* G = (unsigned short*)(dinv + Ma);        // Ma*64 (bf16)
    float* B    = (float*)(G + Ma * DF);             // Ma*64 (fp32 activations)

    const int gN = (M + TB - 1) / TB;
    const int gE = (E + TB - 1) / TB;
    const int nb = (M + TB - 1) / TB;  // scan blocks (196 <= 256)

    // --- CSR build + dinv (once, reused by all 3 layers) ---
    zero_int_kernel<<<gN, TB, 0, stream>>>(deg, M);
    count_deg_kernel<<<gE, TB, 0, stream>>>(dst, deg, E);
    scan_block_kernel<<<nb, TB, 0, stream>>>(deg, rowptr, bsum, dinv, M);
    scan_sums_kernel<<<1, TB, 0, stream>>>(bsum, nb);
    add_offsets_kernel<<<nb, TB, 0, stream>>>(rowptr, bsum, cursor, M);
    fill_csr_kernel<<<gE, TB, 0, stream>>>(src, dst, cursor, cidx, E);

    const dim3 gemmBlk(16, 16);
    const int  gemmGrd = (M + 15) / 16;
    const int  aggGrd  = (M + 3) / 4;

    // --- layer 1 ---
    gemm_kernel<64><<<gemmGrd, gemmBlk, 0, stream>>>(x, W1, dinv, G, M);
    agg_kernel<64, false><<<aggGrd, TB, 0, stream>>>(G, rowptr, deg, cidx, dinv, b1, B, M);
    // --- layer 2 ---
    gemm_kernel<64><<<gemmGrd, gemmBlk, 0, stream>>>(B, W2, dinv, G, M);
    agg_kernel<64, false><<<aggGrd, TB, 0, stream>>>(G, rowptr, deg, cidx, dinv, b2, B, M);
    // --- layer 3 (40 cols) + fused log_softmax ---
    gemm_kernel<40><<<gemmGrd, gemmBlk, 0, stream>>>(B, W3, dinv, G, M);
    agg_kernel<40, true><<<aggGrd, TB, 0, stream>>>(G, rowptr, deg, cidx, dinv, b3, out, M);
}

// Round 4
// 241.357 us; speedup vs baseline: 2.7714x; 1.0044x over previous
//
#include <hip/hip_runtime.h>
#include <math.h>

// ---------------------------------------------------------------------------
// GCN, atomic-free aggregation via per-call CSR (bucket by dst):
//   deg count (dst-partitioned) -> block scan(+dinv) -> fill (dst-partitioned,
//   XCD-local cidx writes, u16)                                   [once]
//   per layer: G = (X@W)*dinv[row]  (GEMM, W in LDS, bf16 out)
//              y[i] = relu( dinv[i]*(G[i] + sum_{e: dst=i} G[src_e]) + b )
//   layers 1-2 emit bf16 activations; layer 3 fuses log_softmax (fp32 out).
// cidx is uint16: valid because N_NODES=50000 < 65536.
// Partitioning: block b owns dst range [(b&7)*psize, ...). With round-robin
// block->XCD dispatch each partition's cursor/cidx lines live in ONE XCD L2,
// killing the 25x partial-line writeback amplification seen in round 3.
// ---------------------------------------------------------------------------

#define DF 64
#define TB 256
#define NPART 8

__device__ __forceinline__ unsigned short f2bf(float f) {
    union { float f; unsigned u; } c; c.f = f;
    unsigned u = c.u;
    return (unsigned short)((u + 0x7fffu + ((u >> 16) & 1u)) >> 16);   // RNE
}
__device__ __forceinline__ float bf2f(unsigned short h) {
    union { unsigned u; float f; } c; c.u = ((unsigned)h) << 16;
    return c.f;
}

__global__ void count_deg_part_kernel(const int* __restrict__ dst, int* __restrict__ deg,
                                      int e, int psize) {
    const int p   = blockIdx.x & (NPART - 1);
    const int sl  = blockIdx.x / NPART;
    const int nsl = gridDim.x / NPART;
    const int lo = p * psize, hi = lo + psize;
    for (int i = sl * TB + threadIdx.x; i < e; i += nsl * TB) {
        int d = dst[i];
        if (d >= lo && d < hi) atomicAdd(&deg[d], 1);
    }
}

// per-block exclusive scan of deg -> ex (partial), block totals -> bsum; also dinv
__global__ void scan_block_kernel(const int* __restrict__ deg, int* __restrict__ ex,
                                  int* __restrict__ bsum, float* __restrict__ dinv, int n) {
    __shared__ int s[TB];
    const int t = threadIdx.x;
    const int i = blockIdx.x * TB + t;
    int v = (i < n) ? deg[i] : 0;
    if (i < n) dinv[i] = rsqrtf((float)(v + 1));   // +1 self-loop
    s[t] = v; __syncthreads();
#pragma unroll
    for (int o = 1; o < TB; o <<= 1) {
        int u = (t >= o) ? s[t - o] : 0;
        __syncthreads();
        s[t] += u;
        __syncthreads();
    }
    if (i < n) ex[i] = s[t] - v;
    if (t == TB - 1) bsum[blockIdx.x] = s[TB - 1];
}

// exclusive scan of block sums (nb <= 256)
__global__ void scan_sums_kernel(int* __restrict__ bsum, int nb) {
    __shared__ int s[TB];
    const int t = threadIdx.x;
    int v = (t < nb) ? bsum[t] : 0;
    s[t] = v; __syncthreads();
#pragma unroll
    for (int o = 1; o < TB; o <<= 1) {
        int u = (t >= o) ? s[t - o] : 0;
        __syncthreads();
        s[t] += u;
        __syncthreads();
    }
    if (t < nb) bsum[t] = s[t] - v;
}

__global__ void add_offsets_kernel(int* __restrict__ ex, const int* __restrict__ bsum,
                                   int* __restrict__ cursor, int n) {
    int i = blockIdx.x * blockDim.x + threadIdx.x;
    if (i < n) {
        int r = ex[i] + bsum[blockIdx.x];   // grid uses TB blocks matching scan
        ex[i] = r;
        cursor[i] = r;
    }
}

__global__ void fill_csr_part_kernel(const int* __restrict__ src, const int* __restrict__ dst,
                                     int* __restrict__ cursor,
                                     unsigned short* __restrict__ cidx, int e, int psize) {
    const int p   = blockIdx.x & (NPART - 1);
    const int sl  = blockIdx.x / NPART;
    const int nsl = gridDim.x / NPART;
    const int lo = p * psize, hi = lo + psize;
    for (int i = sl * TB + threadIdx.x; i < e; i += nsl * TB) {
        int d = dst[i];
        if (d >= lo && d < hi) {
            int pos = atomicAdd(&cursor[d], 1);
            cidx[pos] = (unsigned short)src[i];
        }
    }
}

// G[M x NC](bf16) = (X[M x 64] @ W[64 x NC]) * dinv[row].
// Block (16,16): 16 rows/block, each thread computes 4 cols via float4 W reads.
// TIN = float (layer 1) or unsigned short bf16 (layers 2,3).
template <int NC, typename TIN>
__global__ __launch_bounds__(256) void gemm_kernel(const TIN* __restrict__ X,
                                                   const float* __restrict__ W,
                                                   const float* __restrict__ dinv,
                                                   unsigned short* __restrict__ G, int M) {
    __shared__ float Ws[64 * NC];
    __shared__ float Xs[16][65];
    const int tx = threadIdx.x;            // 0..15 col group
    const int ty = threadIdx.y;            // 0..15 row
    const int tid = ty * 16 + tx;
    for (int i = tid; i < 64 * NC / 4; i += 256)
        ((float4*)Ws)[i] = ((const float4*)W)[i];
    const int row0 = blockIdx.x * 16;
    {   // stage 16 rows of X: 256 threads, 4 cols each
        int r = tid / 16, c4 = tid % 16;
        bool ok = (row0 + r < M);
        if (sizeof(TIN) == 4) {
            const float* Xf = (const float*)X;
            float4 v = ok ? ((const float4*)(Xf + (size_t)(row0 + r) * 64))[c4]
                          : make_float4(0.f, 0.f, 0.f, 0.f);
            Xs[r][c4 * 4 + 0] = v.x; Xs[r][c4 * 4 + 1] = v.y;
            Xs[r][c4 * 4 + 2] = v.z; Xs[r][c4 * 4 + 3] = v.w;
        } else {
            const unsigned short* Xh = (const unsigned short*)X;
            ushort4 v = ok ? ((const ushort4*)(Xh + (size_t)(row0 + r) * 64))[c4]
                           : make_ushort4(0, 0, 0, 0);
            Xs[r][c4 * 4 + 0] = bf2f(v.x); Xs[r][c4 * 4 + 1] = bf2f(v.y);
            Xs[r][c4 * 4 + 2] = bf2f(v.z); Xs[r][c4 * 4 + 3] = bf2f(v.w);
        }
    }
    __syncthreads();
    const int row = row0 + ty;
    const int c0 = tx * 4;
    if (row < M && c0 < NC) {
        float a0 = 0.f, a1 = 0.f, a2 = 0.f, a3 = 0.f;
#pragma unroll
        for (int k = 0; k < 64; ++k) {
            float xk = Xs[ty][k];
            float4 w = ((const float4*)(Ws + (size_t)k * NC))[tx];
            a0 += xk * w.x; a1 += xk * w.y; a2 += xk * w.z; a3 += xk * w.w;
        }
        float di = dinv[row];
        ushort4 o;
        o.x = f2bf(a0 * di); o.y = f2bf(a1 * di);
        o.z = f2bf(a2 * di); o.w = f2bf(a3 * di);
        *((ushort4*)(G + (size_t)row * NC + c0)) = o;
    }
}

// One wave per node: acc = G[i] + sum of G[src] over in-edges;
// y = relu(dinv[i]*acc + b).  TOUT: bf16 (hidden) or float.  LSM: fused log_softmax.
template <int NC, typename TOUT, bool LSM>
__global__ void agg_kernel(const unsigned short* __restrict__ G,
                           const int* __restrict__ rowptr, const int* __restrict__ deg,
                           const unsigned short* __restrict__ cidx,
                           const float* __restrict__ dinv, const float* __restrict__ b,
                           TOUT* __restrict__ Y, int M) {
    const int lane = threadIdx.x & 63;
    const int node = blockIdx.x * 4 + (threadIdx.x >> 6);
    if (node >= M) return;
    const bool act = (lane < NC);
    const int start = rowptr[node];
    const int cnt = deg[node];

    float a0 = act ? bf2f(G[(size_t)node * NC + lane]) : 0.0f;   // self term
    float a1 = 0.f, a2 = 0.f, a3 = 0.f;
    int j = 0;
    for (; j + 3 < cnt; j += 4) {
        int s0 = cidx[start + j];
        int s1 = cidx[start + j + 1];
        int s2 = cidx[start + j + 2];
        int s3 = cidx[start + j + 3];
        if (act) {
            a0 += bf2f(G[(size_t)s0 * NC + lane]);
            a1 += bf2f(G[(size_t)s1 * NC + lane]);
            a2 += bf2f(G[(size_t)s2 * NC + lane]);
            a3 += bf2f(G[(size_t)s3 * NC + lane]);
        }
    }
    for (; j < cnt; ++j) {
        int s = cidx[start + j];
        if (act) a1 += bf2f(G[(size_t)s * NC + lane]);
    }
    float v = (a0 + a1 + a2 + a3) * dinv[node] + (act ? b[lane] : 0.0f);
    v = fmaxf(v, 0.0f);

    if (!LSM) {
        if (act) {
            if (sizeof(TOUT) == 2) ((unsigned short*)Y)[(size_t)node * NC + lane] = f2bf(v);
            else                   ((float*)Y)[(size_t)node * NC + lane] = v;
        }
        return;
    }
    float vm = act ? v : -INFINITY;
    float m = vm;
#pragma unroll
    for (int o = 32; o; o >>= 1) m = fmaxf(m, __shfl_xor(m, o, 64));
    float ex = act ? expf(vm - m) : 0.0f;
    float s = ex;
#pragma unroll
    for (int o = 32; o; o >>= 1) s += __shfl_xor(s, o, 64);
    if (act) ((float*)Y)[(size_t)node * NC + lane] = vm - m - logf(s);
}

extern "C" void kernel_launch(void* const* d_in, const int* in_sizes, int n_in,
                              void* d_out, int out_size, void* d_ws, size_t ws_size,
                              hipStream_t stream) {
    const float* x  = (const float*)d_in[0];
    const int*   ei = (const int*)d_in[1];        // [2, E] int32
    const float* W1 = (const float*)d_in[2];
    const float* b1 = (const float*)d_in[3];
    const float* W2 = (const float*)d_in[4];
    const float* b2 = (const float*)d_in[5];
    const float* W3 = (const float*)d_in[6];
    const float* b3 = (const float*)d_in[7];
    float* out = (float*)d_out;

    const int M  = in_sizes[0] / DF;              // 50000
    const int E  = in_sizes[1] / 2;               // 800000
    (void)ws_size; (void)n_in; (void)out_size;

    const int* src = ei;
    const int* dst = ei + E;

    const size_t Ma = ((size_t)M + 63) & ~63ull;
    const size_t Ea = ((size_t)E + 63) & ~63ull;

    // workspace layout
    int* deg    = (int*)d_ws;                            // Ma
    int* rowptr = deg + Ma;                              // Ma
    int* cursor = rowptr + Ma;                           // Ma
    int* bsum   = cursor + Ma;                           // 256
    unsigned short* cidx = (unsigned short*)(bsum + 256);        // Ea (u16)
    float* dinv = (float*)(cidx + Ea);                   // Ma
    unsigned short* G    = (unsigned short*)(dinv + Ma);         // Ma*64 (bf16)
    unsigned short* Bact = G + Ma * DF;                  // Ma*64 (bf16 activations)

    const int nb = (M + TB - 1) / TB;   // scan blocks (196 <= 256)
    const int psize = (M + NPART - 1) / NPART;
    const int partGrd = NPART * 96;     // 8 partitions x 96 slices

    // --- CSR build + dinv (once, reused by all 3 layers) ---
    hipMemsetAsync(deg, 0, Ma * sizeof(int), stream);
    count_deg_part_kernel<<<partGrd, TB, 0, stream>>>(dst, deg, E, psize);
    scan_block_kernel<<<nb, TB, 0, stream>>>(deg, rowptr, bsum, dinv, M);
    scan_sums_kernel<<<1, TB, 0, stream>>>(bsum, nb);
    add_offsets_kernel<<<nb, TB, 0, stream>>>(rowptr, bsum, cursor, M);
    fill_csr_part_kernel<<<partGrd, TB, 0, stream>>>(src, dst, cursor, cidx, E, psize);

    const dim3 gemmBlk(16, 16);
    const int  gemmGrd = (M + 15) / 16;
    const int  aggGrd  = (M + 3) / 4;

    // --- layer 1 ---
    gemm_kernel<64, float><<<gemmGrd, gemmBlk, 0, stream>>>(x, W1, dinv, G, M);
    agg_kernel<64, unsigned short, false><<<aggGrd, TB, 0, stream>>>(G, rowptr, deg, cidx, dinv, b1, Bact, M);
    // --- layer 2 ---
    gemm_kernel<64, unsigned short><<<gemmGrd, gemmBlk, 0, stream>>>(Bact, W2, dinv, G, M);
    agg_kernel<64, unsigned short, false><<<aggGrd, TB, 0, stream>>>(G, rowptr, deg, cidx, dinv, b2, Bact, M);
    // --- layer 3 (40 cols) + fused log_softmax ---
    gemm_kernel<40, unsigned short><<<gemmGrd, gemmBlk, 0, stream>>>(Bact, W3, dinv, G, M);
    agg_kernel<40, float, true><<<aggGrd, TB, 0, stream>>>(G, rowptr, deg, cidx, dinv, b3, out, M);
}

// Round 5
// 224.727 us; speedup vs baseline: 2.9765x; 1.0740x over previous
//
#include <hip/hip_runtime.h>
#include <math.h>

// ---------------------------------------------------------------------------
// GCN, atomic-free aggregation via per-call CSR (bucket by dst):
//   deg count (dst-partitioned) -> block scan(+dinv) -> fill (dst-partitioned,
//   XCD-local cidx writes, u16)                                   [once]
//   per layer: G = (X@W)*dinv[row]  (GEMM, W in LDS, bf16 out)
//              y[i] = relu( dinv[i]*(G[i] + sum_{e: dst=i} G[src_e]) + b )
//   layers 1-2 emit bf16 activations; layer 3 fuses log_softmax (fp32 out).
// cidx is uint16 (N_NODES=50000 < 65536). agg loads 64 edge indices per
// coalesced wave read, broadcasts via __shfl -> gathers pipeline freely.
// NOTE: no hipMemsetAsync — rocclr fillBuffer took 45.9us for 195KB in-graph.
// ---------------------------------------------------------------------------

#define DF 64
#define TB 256
#define NPART 8

__device__ __forceinline__ unsigned short f2bf(float f) {
    union { float f; unsigned u; } c; c.f = f;
    unsigned u = c.u;
    return (unsigned short)((u + 0x7fffu + ((u >> 16) & 1u)) >> 16);   // RNE
}
__device__ __forceinline__ float bf2f(unsigned short h) {
    union { unsigned u; float f; } c; c.u = ((unsigned)h) << 16;
    return c.f;
}

__global__ void zero_int_kernel(int* __restrict__ p, int n) {
    int i = blockIdx.x * blockDim.x + threadIdx.x;
    if (i < n) p[i] = 0;
}

__global__ void count_deg_part_kernel(const int* __restrict__ dst, int* __restrict__ deg,
                                      int e, int psize) {
    const int p   = blockIdx.x & (NPART - 1);
    const int sl  = blockIdx.x / NPART;
    const int nsl = gridDim.x / NPART;
    const int lo = p * psize, hi = lo + psize;
    for (int i = sl * TB + threadIdx.x; i < e; i += nsl * TB) {
        int d = dst[i];
        if (d >= lo && d < hi) atomicAdd(&deg[d], 1);
    }
}

// per-block exclusive scan of deg -> ex (partial), block totals -> bsum; also dinv
__global__ void scan_block_kernel(const int* __restrict__ deg, int* __restrict__ ex,
                                  int* __restrict__ bsum, float* __restrict__ dinv, int n) {
    __shared__ int s[TB];
    const int t = threadIdx.x;
    const int i = blockIdx.x * TB + t;
    int v = (i < n) ? deg[i] : 0;
    if (i < n) dinv[i] = rsqrtf((float)(v + 1));   // +1 self-loop
    s[t] = v; __syncthreads();
#pragma unroll
    for (int o = 1; o < TB; o <<= 1) {
        int u = (t >= o) ? s[t - o] : 0;
        __syncthreads();
        s[t] += u;
        __syncthreads();
    }
    if (i < n) ex[i] = s[t] - v;
    if (t == TB - 1) bsum[blockIdx.x] = s[TB - 1];
}

// exclusive scan of block sums (nb <= 256)
__global__ void scan_sums_kernel(int* __restrict__ bsum, int nb) {
    __shared__ int s[TB];
    const int t = threadIdx.x;
    int v = (t < nb) ? bsum[t] : 0;
    s[t] = v; __syncthreads();
#pragma unroll
    for (int o = 1; o < TB; o <<= 1) {
        int u = (t >= o) ? s[t - o] : 0;
        __syncthreads();
        s[t] += u;
        __syncthreads();
    }
    if (t < nb) bsum[t] = s[t] - v;
}

__global__ void add_offsets_kernel(int* __restrict__ ex, const int* __restrict__ bsum,
                                   int* __restrict__ cursor, int n) {
    int i = blockIdx.x * blockDim.x + threadIdx.x;
    if (i < n) {
        int r = ex[i] + bsum[blockIdx.x];   // grid uses TB blocks matching scan
        ex[i] = r;
        cursor[i] = r;
    }
}

__global__ void fill_csr_part_kernel(const int* __restrict__ src, const int* __restrict__ dst,
                                     int* __restrict__ cursor,
                                     unsigned short* __restrict__ cidx, int e, int psize) {
    const int p   = blockIdx.x & (NPART - 1);
    const int sl  = blockIdx.x / NPART;
    const int nsl = gridDim.x / NPART;
    const int lo = p * psize, hi = lo + psize;
    for (int i = sl * TB + threadIdx.x; i < e; i += nsl * TB) {
        int d = dst[i];
        if (d >= lo && d < hi) {
            int pos = atomicAdd(&cursor[d], 1);
            cidx[pos] = (unsigned short)src[i];
        }
    }
}

// G[M x NC](bf16) = (X[M x 64] @ W[64 x NC]) * dinv[row].
// Block (16,16): 16 rows/block, each thread computes 4 cols via float4 W reads.
template <int NC, typename TIN>
__global__ __launch_bounds__(256) void gemm_kernel(const TIN* __restrict__ X,
                                                   const float* __restrict__ W,
                                                   const float* __restrict__ dinv,
                                                   unsigned short* __restrict__ G, int M) {
    __shared__ float Ws[64 * NC];
    __shared__ float Xs[16][65];
    const int tx = threadIdx.x;            // 0..15 col group
    const int ty = threadIdx.y;            // 0..15 row
    const int tid = ty * 16 + tx;
    for (int i = tid; i < 64 * NC / 4; i += 256)
        ((float4*)Ws)[i] = ((const float4*)W)[i];
    const int row0 = blockIdx.x * 16;
    {   // stage 16 rows of X: 256 threads, 4 cols each
        int r = tid / 16, c4 = tid % 16;
        bool ok = (row0 + r < M);
        if (sizeof(TIN) == 4) {
            const float* Xf = (const float*)X;
            float4 v = ok ? ((const float4*)(Xf + (size_t)(row0 + r) * 64))[c4]
                          : make_float4(0.f, 0.f, 0.f, 0.f);
            Xs[r][c4 * 4 + 0] = v.x; Xs[r][c4 * 4 + 1] = v.y;
            Xs[r][c4 * 4 + 2] = v.z; Xs[r][c4 * 4 + 3] = v.w;
        } else {
            const unsigned short* Xh = (const unsigned short*)X;
            ushort4 v = ok ? ((const ushort4*)(Xh + (size_t)(row0 + r) * 64))[c4]
                           : make_ushort4(0, 0, 0, 0);
            Xs[r][c4 * 4 + 0] = bf2f(v.x); Xs[r][c4 * 4 + 1] = bf2f(v.y);
            Xs[r][c4 * 4 + 2] = bf2f(v.z); Xs[r][c4 * 4 + 3] = bf2f(v.w);
        }
    }
    __syncthreads();
    const int row = row0 + ty;
    const int c0 = tx * 4;
    if (row < M && c0 < NC) {
        float a0 = 0.f, a1 = 0.f, a2 = 0.f, a3 = 0.f;
#pragma unroll
        for (int k = 0; k < 64; ++k) {
            float xk = Xs[ty][k];
            float4 w = ((const float4*)(Ws + (size_t)k * NC))[tx];
            a0 += xk * w.x; a1 += xk * w.y; a2 += xk * w.z; a3 += xk * w.w;
        }
        float di = dinv[row];
        ushort4 o;
        o.x = f2bf(a0 * di); o.y = f2bf(a1 * di);
        o.z = f2bf(a2 * di); o.w = f2bf(a3 * di);
        *((ushort4*)(G + (size_t)row * NC + c0)) = o;
    }
}

// One wave per node. Edge indices loaded 64-at-a-time coalesced (per lane),
// broadcast via __shfl; gathers pipeline with 4 accumulators.
// y = relu(dinv[i]*(G[i] + sum G[src]) + b). TOUT bf16/float; LSM fuses log_softmax.
template <int NC, typename TOUT, bool LSM>
__global__ void agg_kernel(const unsigned short* __restrict__ G,
                           const int* __restrict__ rowptr, const int* __restrict__ deg,
                           const unsigned short* __restrict__ cidx,
                           const float* __restrict__ dinv, const float* __restrict__ b,
                           TOUT* __restrict__ Y, int M) {
    const int lane = threadIdx.x & 63;
    const int node = blockIdx.x * 4 + (threadIdx.x >> 6);
    if (node >= M) return;
    const bool act = (lane < NC);
    const int start = rowptr[node];
    const int cnt = deg[node];

    float a0 = act ? bf2f(G[(size_t)node * NC + lane]) : 0.0f;   // self term
    float a1 = 0.f, a2 = 0.f, a3 = 0.f;

    for (int base = 0; base < cnt; base += 64) {
        const int nthis = min(64, cnt - base);
        // one coalesced wave read covers up to 64 edge indices
        int myidx = (lane < nthis) ? (int)cidx[start + base + lane] : 0;
        int j = 0;
        for (; j + 3 < nthis; j += 4) {
            int s0 = __shfl(myidx, j, 64);
            int s1 = __shfl(myidx, j + 1, 64);
            int s2 = __shfl(myidx, j + 2, 64);
            int s3 = __shfl(myidx, j + 3, 64);
            if (act) {
                a0 += bf2f(G[(size_t)s0 * NC + lane]);
                a1 += bf2f(G[(size_t)s1 * NC + lane]);
                a2 += bf2f(G[(size_t)s2 * NC + lane]);
                a3 += bf2f(G[(size_t)s3 * NC + lane]);
            }
        }
        for (; j < nthis; ++j) {
            int s = __shfl(myidx, j, 64);
            if (act) a1 += bf2f(G[(size_t)s * NC + lane]);
        }
    }
    float v = (a0 + a1 + a2 + a3) * dinv[node] + (act ? b[lane] : 0.0f);
    v = fmaxf(v, 0.0f);

    if (!LSM) {
        if (act) {
            if (sizeof(TOUT) == 2) ((unsigned short*)Y)[(size_t)node * NC + lane] = f2bf(v);
            else                   ((float*)Y)[(size_t)node * NC + lane] = v;
        }
        return;
    }
    float vm = act ? v : -INFINITY;
    float m = vm;
#pragma unroll
    for (int o = 32; o; o >>= 1) m = fmaxf(m, __shfl_xor(m, o, 64));
    float ex = act ? expf(vm - m) : 0.0f;
    float s = ex;
#pragma unroll
    for (int o = 32; o; o >>= 1) s += __shfl_xor(s, o, 64);
    if (act) ((float*)Y)[(size_t)node * NC + lane] = vm - m - logf(s);
}

extern "C" void kernel_launch(void* const* d_in, const int* in_sizes, int n_in,
                              void* d_out, int out_size, void* d_ws, size_t ws_size,
                              hipStream_t stream) {
    const float* x  = (const float*)d_in[0];
    const int*   ei = (const int*)d_in[1];        // [2, E] int32
    const float* W1 = (const float*)d_in[2];
    const float* b1 = (const float*)d_in[3];
    const float* W2 = (const float*)d_in[4];
    const float* b2 = (const float*)d_in[5];
    const float* W3 = (const float*)d_in[6];
    const float* b3 = (const float*)d_in[7];
    float* out = (float*)d_out;

    const int M  = in_sizes[0] / DF;              // 50000
    const int E  = in_sizes[1] / 2;               // 800000
    (void)ws_size; (void)n_in; (void)out_size;

    const int* src = ei;
    const int* dst = ei + E;

    const size_t Ma = ((size_t)M + 63) & ~63ull;
    const size_t Ea = ((size_t)E + 63) & ~63ull;

    // workspace layout
    int* deg    = (int*)d_ws;                            // Ma
    int* rowptr = deg + Ma;                              // Ma
    int* cursor = rowptr + Ma;                           // Ma
    int* bsum   = cursor + Ma;                           // 256
    unsigned short* cidx = (unsigned short*)(bsum + 256);        // Ea (u16)
    float* dinv = (float*)(cidx + Ea);                   // Ma
    unsigned short* G    = (unsigned short*)(dinv + Ma);         // Ma*64 (bf16)
    unsigned short* Bact = G + Ma * DF;                  // Ma*64 (bf16 activations)

    const int gN = (M + TB - 1) / TB;
    const int nb = gN;                   // scan blocks (196 <= 256)
    const int psize = (M + NPART - 1) / NPART;
    const int partGrd = NPART * 96;      // 8 partitions x 96 slices

    // --- CSR build + dinv (once, reused by all 3 layers) ---
    zero_int_kernel<<<gN, TB, 0, stream>>>(deg, M);
    count_deg_part_kernel<<<partGrd, TB, 0, stream>>>(dst, deg, E, psize);
    scan_block_kernel<<<nb, TB, 0, stream>>>(deg, rowptr, bsum, dinv, M);
    scan_sums_kernel<<<1, TB, 0, stream>>>(bsum, nb);
    add_offsets_kernel<<<nb, TB, 0, stream>>>(rowptr, bsum, cursor, M);
    fill_csr_part_kernel<<<partGrd, TB, 0, stream>>>(src, dst, cursor, cidx, E, psize);

    const dim3 gemmBlk(16, 16);
    const int  gemmGrd = (M + 15) / 16;
    const int  aggGrd  = (M + 3) / 4;

    // --- layer 1 ---
    gemm_kernel<64, float><<<gemmGrd, gemmBlk, 0, stream>>>(x, W1, dinv, G, M);
    agg_kernel<64, unsigned short, false><<<aggGrd, TB, 0, stream>>>(G, rowptr, deg, cidx, dinv, b1, Bact, M);
    // --- layer 2 ---
    gemm_kernel<64, unsigned short><<<gemmGrd, gemmBlk, 0, stream>>>(Bact, W2, dinv, G, M);
    agg_kernel<64, unsigned short, false><<<aggGrd, TB, 0, stream>>>(G, rowptr, deg, cidx, dinv, b2, Bact, M);
    // --- layer 3 (40 cols) + fused log_softmax ---
    gemm_kernel<40, unsigned short><<<gemmGrd, gemmBlk, 0, stream>>>(Bact, W3, dinv, G, M);
    agg_kernel<40, float, true><<<aggGrd, TB, 0, stream>>>(G, rowptr, deg, cidx, dinv, b3, out, M);
}

// Round 6
// 214.950 us; speedup vs baseline: 3.1119x; 1.0455x over previous
//
#include <hip/hip_runtime.h>
#include <math.h>

// ---------------------------------------------------------------------------
// GCN, atomic-free aggregation via per-call CSR (bucket by dst):
//   deg count (dst-partitioned) -> block scan(+dinv) -> add_offsets (fused
//   bsum scan) -> fill (dst-partitioned, XCD-local, u16)          [once]
//   per layer: G = (X@W)*dinv[row]  (GEMM, W in LDS, bf16 out)
//              y[i] = relu( dinv[i]*(G[i] + sum_{e: dst=i} G[src_e]) + b )
//   layers 1-2 emit bf16 activations; layer 3 fuses log_softmax (fp32 out).
// agg: one wave per node; each lane owns 4 cols (uint2 bf16x4 loads); the 4
// groups of 16 lanes gather 4 DIFFERENT edge rows per instruction (512B/instr)
// and partials are merged with shfl_xor(16|32). 4x fewer gather issues.
// cidx is uint16 (N_NODES=50000 < 65536).
// NOTE: no hipMemsetAsync — rocclr fillBuffer took 45.9us for 195KB in-graph.
// ---------------------------------------------------------------------------

#define DF 64
#define TB 256
#define NPART 8

__device__ __forceinline__ unsigned short f2bf(float f) {
    union { float f; unsigned u; } c; c.f = f;
    unsigned u = c.u;
    return (unsigned short)((u + 0x7fffu + ((u >> 16) & 1u)) >> 16);   // RNE
}
__device__ __forceinline__ float bf2f(unsigned short h) {
    union { unsigned u; float f; } c; c.u = ((unsigned)h) << 16;
    return c.f;
}
__device__ __forceinline__ void acc_bf16x4(uint2 v, float* a) {
    a[0] += bf2f((unsigned short)(v.x & 0xffffu));
    a[1] += bf2f((unsigned short)(v.x >> 16));
    a[2] += bf2f((unsigned short)(v.y & 0xffffu));
    a[3] += bf2f((unsigned short)(v.y >> 16));
}

__global__ void zero_int_kernel(int* __restrict__ p, int n) {
    int i = blockIdx.x * blockDim.x + threadIdx.x;
    if (i < n) p[i] = 0;
}

__global__ void count_deg_part_kernel(const int* __restrict__ dst, int* __restrict__ deg,
                                      int e, int psize) {
    const int p   = blockIdx.x & (NPART - 1);
    const int sl  = blockIdx.x / NPART;
    const int nsl = gridDim.x / NPART;
    const int lo = p * psize, hi = lo + psize;
    for (int i = sl * TB + threadIdx.x; i < e; i += nsl * TB) {
        int d = dst[i];
        if (d >= lo && d < hi) atomicAdd(&deg[d], 1);
    }
}

// per-block exclusive scan of deg -> ex (partial), block totals -> bsum; also dinv
__global__ void scan_block_kernel(const int* __restrict__ deg, int* __restrict__ ex,
                                  int* __restrict__ bsum, float* __restrict__ dinv, int n) {
    __shared__ int s[TB];
    const int t = threadIdx.x;
    const int i = blockIdx.x * TB + t;
    int v = (i < n) ? deg[i] : 0;
    if (i < n) dinv[i] = rsqrtf((float)(v + 1));   // +1 self-loop
    s[t] = v; __syncthreads();
#pragma unroll
    for (int o = 1; o < TB; o <<= 1) {
        int u = (t >= o) ? s[t - o] : 0;
        __syncthreads();
        s[t] += u;
        __syncthreads();
    }
    if (i < n) ex[i] = s[t] - v;
    if (t == TB - 1) bsum[blockIdx.x] = s[TB - 1];
}

// each block redundantly scans bsum (nb <= 256) in LDS, then offsets its slice
__global__ void add_offsets_kernel(int* __restrict__ ex, const int* __restrict__ bsum,
                                   int* __restrict__ cursor, int n, int nb) {
    __shared__ int s[TB];
    const int t = threadIdx.x;
    int v = (t < nb) ? bsum[t] : 0;
    s[t] = v; __syncthreads();
#pragma unroll
    for (int o = 1; o < TB; o <<= 1) {
        int u = (t >= o) ? s[t - o] : 0;
        __syncthreads();
        s[t] += u;
        __syncthreads();
    }
    const int boff = (blockIdx.x > 0) ? s[blockIdx.x - 1] : 0;
    const int i = blockIdx.x * TB + t;
    if (i < n) {
        int r = ex[i] + boff;
        ex[i] = r;
        cursor[i] = r;
    }
}

__global__ void fill_csr_part_kernel(const int* __restrict__ src, const int* __restrict__ dst,
                                     int* __restrict__ cursor,
                                     unsigned short* __restrict__ cidx, int e, int psize) {
    const int p   = blockIdx.x & (NPART - 1);
    const int sl  = blockIdx.x / NPART;
    const int nsl = gridDim.x / NPART;
    const int lo = p * psize, hi = lo + psize;
    for (int i = sl * TB + threadIdx.x; i < e; i += nsl * TB) {
        int d = dst[i];
        if (d >= lo && d < hi) {
            int pos = atomicAdd(&cursor[d], 1);
            cidx[pos] = (unsigned short)src[i];
        }
    }
}

// G[M x NC](bf16) = (X[M x 64] @ W[64 x NC]) * dinv[row].
// Block (16,16): 16 rows/block, each thread computes 4 cols via float4 W reads.
template <int NC, typename TIN>
__global__ __launch_bounds__(256) void gemm_kernel(const TIN* __restrict__ X,
                                                   const float* __restrict__ W,
                                                   const float* __restrict__ dinv,
                                                   unsigned short* __restrict__ G, int M) {
    __shared__ float Ws[64 * NC];
    __shared__ float Xs[16][65];
    const int tx = threadIdx.x;            // 0..15 col group
    const int ty = threadIdx.y;            // 0..15 row
    const int tid = ty * 16 + tx;
    for (int i = tid; i < 64 * NC / 4; i += 256)
        ((float4*)Ws)[i] = ((const float4*)W)[i];
    const int row0 = blockIdx.x * 16;
    {   // stage 16 rows of X: 256 threads, 4 cols each
        int r = tid / 16, c4 = tid % 16;
        bool ok = (row0 + r < M);
        if (sizeof(TIN) == 4) {
            const float* Xf = (const float*)X;
            float4 v = ok ? ((const float4*)(Xf + (size_t)(row0 + r) * 64))[c4]
                          : make_float4(0.f, 0.f, 0.f, 0.f);
            Xs[r][c4 * 4 + 0] = v.x; Xs[r][c4 * 4 + 1] = v.y;
            Xs[r][c4 * 4 + 2] = v.z; Xs[r][c4 * 4 + 3] = v.w;
        } else {
            const unsigned short* Xh = (const unsigned short*)X;
            ushort4 v = ok ? ((const ushort4*)(Xh + (size_t)(row0 + r) * 64))[c4]
                           : make_ushort4(0, 0, 0, 0);
            Xs[r][c4 * 4 + 0] = bf2f(v.x); Xs[r][c4 * 4 + 1] = bf2f(v.y);
            Xs[r][c4 * 4 + 2] = bf2f(v.z); Xs[r][c4 * 4 + 3] = bf2f(v.w);
        }
    }
    __syncthreads();
    const int row = row0 + ty;
    const int c0 = tx * 4;
    if (row < M && c0 < NC) {
        float a0 = 0.f, a1 = 0.f, a2 = 0.f, a3 = 0.f;
#pragma unroll
        for (int k = 0; k < 64; ++k) {
            float xk = Xs[ty][k];
            float4 w = ((const float4*)(Ws + (size_t)k * NC))[tx];
            a0 += xk * w.x; a1 += xk * w.y; a2 += xk * w.z; a3 += xk * w.w;
        }
        float di = dinv[row];
        ushort4 o;
        o.x = f2bf(a0 * di); o.y = f2bf(a1 * di);
        o.z = f2bf(a2 * di); o.w = f2bf(a3 * di);
        *((ushort4*)(G + (size_t)row * NC + c0)) = o;
    }
}

// One wave per node. lane = grp(2b)*16 + sub(4b): lane owns cols [sub*4, sub*4+4);
// group grp gathers edge rows (4j+grp). uint2 bf16x4 loads, 4 rows / instruction.
// Partials merged across groups via shfl_xor(16|32) at the end.
// y = relu(dinv[i]*(G[i] + sum G[src]) + b). TOUT bf16/float; LSM fuses log_softmax.
template <int NC, typename TOUT, bool LSM>
__global__ void agg_kernel(const unsigned short* __restrict__ G,
                           const int* __restrict__ rowptr, const int* __restrict__ deg,
                           const unsigned short* __restrict__ cidx,
                           const float* __restrict__ dinv, const float* __restrict__ b,
                           TOUT* __restrict__ Y, int M) {
    constexpr int NQ = NC / 4;                 // col-quads per row (16 or 10)
    const int lane = threadIdx.x & 63;
    const int node = blockIdx.x * 4 + (threadIdx.x >> 6);
    if (node >= M) return;
    const int grp = lane >> 4;                 // 0..3  edge slot
    const int sub = lane & 15;                 // 0..15 col quad
    const bool act = (sub < NQ);
    const int start = rowptr[node];
    const int cnt = deg[node];

    float a[4] = {0.f, 0.f, 0.f, 0.f};
    float c[4] = {0.f, 0.f, 0.f, 0.f};

    for (int base = 0; base < cnt; base += 64) {
        const int nthis = min(64, cnt - base);
        int myidx = (lane < nthis) ? (int)cidx[start + base + lane] : 0;
        int j = 0;
        for (; j + 8 <= nthis; j += 8) {
            int s0 = __shfl(myidx, j + grp, 64);
            int s1 = __shfl(myidx, j + 4 + grp, 64);
            if (act) {
                uint2 v0 = *(const uint2*)(G + (size_t)s0 * NC + sub * 4);
                uint2 v1 = *(const uint2*)(G + (size_t)s1 * NC + sub * 4);
                acc_bf16x4(v0, a);
                acc_bf16x4(v1, c);
            }
        }
        if (j + 4 <= nthis) {
            int s0 = __shfl(myidx, j + grp, 64);
            if (act) {
                uint2 v0 = *(const uint2*)(G + (size_t)s0 * NC + sub * 4);
                acc_bf16x4(v0, a);
            }
            j += 4;
        }
        const int rem = nthis - j;             // 0..3
        if (grp < rem) {
            int s0 = __shfl(myidx, j + grp, 64);
            if (act) {
                uint2 v0 = *(const uint2*)(G + (size_t)s0 * NC + sub * 4);
                acc_bf16x4(v0, c);
            }
        }
    }
#pragma unroll
    for (int k = 0; k < 4; ++k) a[k] += c[k];
#pragma unroll
    for (int k = 0; k < 4; ++k) {
        a[k] += __shfl_xor(a[k], 16, 64);
        a[k] += __shfl_xor(a[k], 32, 64);
    }
    // self term + bias + relu (all lanes hold the group-merged sums now)
    float v[4];
    {
        float self[4] = {0.f, 0.f, 0.f, 0.f};
        float4 bb = make_float4(0.f, 0.f, 0.f, 0.f);
        if (act) {
            uint2 sv = *(const uint2*)(G + (size_t)node * NC + sub * 4);
            self[0] = bf2f((unsigned short)(sv.x & 0xffffu));
            self[1] = bf2f((unsigned short)(sv.x >> 16));
            self[2] = bf2f((unsigned short)(sv.y & 0xffffu));
            self[3] = bf2f((unsigned short)(sv.y >> 16));
            bb = *(const float4*)(b + sub * 4);
        }
        const float di = dinv[node];
        v[0] = fmaxf((a[0] + self[0]) * di + bb.x, 0.f);
        v[1] = fmaxf((a[1] + self[1]) * di + bb.y, 0.f);
        v[2] = fmaxf((a[2] + self[2]) * di + bb.z, 0.f);
        v[3] = fmaxf((a[3] + self[3]) * di + bb.w, 0.f);
    }

    if (!LSM) {
        if (act && grp == 0) {
            if (sizeof(TOUT) == 2) {
                ushort4 o;
                o.x = f2bf(v[0]); o.y = f2bf(v[1]); o.z = f2bf(v[2]); o.w = f2bf(v[3]);
                *((ushort4*)((unsigned short*)Y + (size_t)node * NC + sub * 4)) = o;
            } else {
                *((float4*)((float*)Y + (size_t)node * NC + sub * 4)) =
                    make_float4(v[0], v[1], v[2], v[3]);
            }
        }
        return;
    }
    // fused log_softmax across the row (cols live on sub=0..NQ-1, 4 each)
    float m = act ? fmaxf(fmaxf(v[0], v[1]), fmaxf(v[2], v[3])) : -INFINITY;
#pragma unroll
    for (int o = 1; o < 16; o <<= 1) m = fmaxf(m, __shfl_xor(m, o, 64));
    float es = act ? (expf(v[0] - m) + expf(v[1] - m) + expf(v[2] - m) + expf(v[3] - m)) : 0.f;
#pragma unroll
    for (int o = 1; o < 16; o <<= 1) es += __shfl_xor(es, o, 64);
    const float ls = logf(es);
    if (act && grp == 0) {
        *((float4*)((float*)Y + (size_t)node * NC + sub * 4)) =
            make_float4(v[0] - m - ls, v[1] - m - ls, v[2] - m - ls, v[3] - m - ls);
    }
}

extern "C" void kernel_launch(void* const* d_in, const int* in_sizes, int n_in,
                              void* d_out, int out_size, void* d_ws, size_t ws_size,
                              hipStream_t stream) {
    const float* x  = (const float*)d_in[0];
    const int*   ei = (const int*)d_in[1];        // [2, E] int32
    const float* W1 = (const float*)d_in[2];
    const float* b1 = (const float*)d_in[3];
    const float* W2 = (const float*)d_in[4];
    const float* b2 = (const float*)d_in[5];
    const float* W3 = (const float*)d_in[6];
    const float* b3 = (const float*)d_in[7];
    float* out = (float*)d_out;

    const int M  = in_sizes[0] / DF;              // 50000
    const int E  = in_sizes[1] / 2;               // 800000
    (void)ws_size; (void)n_in; (void)out_size;

    const int* src = ei;
    const int* dst = ei + E;

    const size_t Ma = ((size_t)M + 63) & ~63ull;
    const size_t Ea = ((size_t)E + 63) & ~63ull;

    // workspace layout
    int* deg    = (int*)d_ws;                            // Ma
    int* rowptr = deg + Ma;                              // Ma
    int* cursor = rowptr + Ma;                           // Ma
    int* bsum   = cursor + Ma;                           // 256
    unsigned short* cidx = (unsigned short*)(bsum + 256);        // Ea (u16)
    float* dinv = (float*)(cidx + Ea);                   // Ma
    unsigned short* G    = (unsigned short*)(dinv + Ma);         // Ma*64 (bf16)
    unsigned short* Bact = G + Ma * DF;                  // Ma*64 (bf16 activations)

    const int gN = (M + TB - 1) / TB;
    const int nb = gN;                   // scan blocks (196 <= 256)
    const int psize = (M + NPART - 1) / NPART;
    const int partGrd = NPART * 96;      // 8 partitions x 96 slices

    // --- CSR build + dinv (once, reused by all 3 layers) ---
    zero_int_kernel<<<gN, TB, 0, stream>>>(deg, M);
    count_deg_part_kernel<<<partGrd, TB, 0, stream>>>(dst, deg, E, psize);
    scan_block_kernel<<<nb, TB, 0, stream>>>(deg, rowptr, bsum, dinv, M);
    add_offsets_kernel<<<nb, TB, 0, stream>>>(rowptr, bsum, cursor, M, nb);
    fill_csr_part_kernel<<<partGrd, TB, 0, stream>>>(src, dst, cursor, cidx, E, psize);

    const dim3 gemmBlk(16, 16);
    const int  gemmGrd = (M + 15) / 16;
    const int  aggGrd  = (M + 3) / 4;

    // --- layer 1 ---
    gemm_kernel<64, float><<<gemmGrd, gemmBlk, 0, stream>>>(x, W1, dinv, G, M);
    agg_kernel<64, unsigned short, false><<<aggGrd, TB, 0, stream>>>(G, rowptr, deg, cidx, dinv, b1, Bact, M);
    // --- layer 2 ---
    gemm_kernel<64, unsigned short><<<gemmGrd, gemmBlk, 0, stream>>>(Bact, W2, dinv, G, M);
    agg_kernel<64, unsigned short, false><<<aggGrd, TB, 0, stream>>>(G, rowptr, deg, cidx, dinv, b2, Bact, M);
    // --- layer 3 (40 cols) + fused log_softmax ---
    gemm_kernel<40, unsigned short><<<gemmGrd, gemmBlk, 0, stream>>>(Bact, W3, dinv, G, M);
    agg_kernel<40, float, true><<<aggGrd, TB, 0, stream>>>(G, rowptr, deg, cidx, dinv, b3, out, M);
}